// Round 9
// baseline (397.839 us; speedup 1.0000x reference)
//
#include <hip/hip_runtime.h>

#define T_TOK 16384
#define H_DIM 4096
#define O_DIM 4096
#define NA 8
#define RANK 16

typedef float f32x4 __attribute__((ext_vector_type(4)));
typedef short bf16x8 __attribute__((ext_vector_type(8)));
typedef short s16x8 __attribute__((ext_vector_type(8)));

// f32 -> bf16 (RTNE)
static __device__ __forceinline__ unsigned short f2bf(float f) {
    unsigned int u = __float_as_uint(f);
    u = (u + 0x7fffu + ((u >> 16) & 1u)) >> 16;
    return (unsigned short)u;
}

// ---------------- sort-by-adapter machinery ----------------

__global__ void k_zero(int* __restrict__ counts) {
    if (threadIdx.x < NA) counts[threadIdx.x] = 0;
}

__global__ void k_hist(const int* __restrict__ idx, int* __restrict__ counts) {
    __shared__ int h[NA];
    if (threadIdx.x < NA) h[threadIdx.x] = 0;
    __syncthreads();
    int t = blockIdx.x * blockDim.x + threadIdx.x;
    atomicAdd(&h[idx[t]], 1);
    __syncthreads();
    if (threadIdx.x < NA) atomicAdd(&counts[threadIdx.x], h[threadIdx.x]);
}

__global__ void k_prefix(const int* __restrict__ counts, int* __restrict__ offs,
                         int* __restrict__ cursor) {
    if (threadIdx.x == 0) {
        int run = 0;
        for (int n = 0; n < NA; n++) { offs[n] = run; cursor[n] = run; run += counts[n]; }
    }
}

__global__ void k_scatter(const int* __restrict__ idx, int* __restrict__ cursor,
                          int* __restrict__ order) {
    int t = blockIdx.x * blockDim.x + threadIdx.x;
    int a = idx[t];
    int lane = threadIdx.x & 63;
    for (int n = 0; n < NA; n++) {
        unsigned long long m = __ballot(a == n);
        if (m) {
            int leader = __ffsll((unsigned long long)m) - 1;
            int cnt = __popcll(m);
            int base = 0;
            if (lane == leader) base = atomicAdd(&cursor[n], cnt);
            base = __shfl(base, leader);
            if (a == n) {
                int rank = __popcll(m & ((1ull << lane) - 1ull));
                order[base + rank] = t;
            }
        }
    }
}

// ---------------- transpose A -> ATb[n][r][h] (bf16) ----------------

__global__ void k_transpose(const float* __restrict__ A, unsigned short* __restrict__ ATb) {
    const int n = blockIdx.y;
    const int h0 = blockIdx.x * 256;
    __shared__ float lds[256 * 17];
    const float4* src = (const float4*)(A + ((size_t)n * H_DIM + h0) * RANK);
#pragma unroll
    for (int k = 0; k < 4; ++k) {
        int f = k * 256 + threadIdx.x;
        float4 v = src[f];
        int row = (f * 4) >> 4, col = (f * 4) & 15;
        lds[row * 17 + col + 0] = v.x;
        lds[row * 17 + col + 1] = v.y;
        lds[row * 17 + col + 2] = v.z;
        lds[row * 17 + col + 3] = v.w;
    }
    __syncthreads();
    unsigned short* dst = ATb + (size_t)n * RANK * H_DIM;
#pragma unroll
    for (int r = 0; r < RANK; ++r)
        dst[(size_t)r * H_DIM + h0 + threadIdx.x] = f2bf(lds[threadIdx.x * 17 + r]);
}

// ---------------- transpose B -> BTb[n][o][r] (bf16) ----------------
// reads coalesced per rank-row; each thread writes its col's 16 ranks (32B contiguous)

__global__ void k_transposeB(const float* __restrict__ B, unsigned short* __restrict__ BTb) {
    const int n = blockIdx.y;
    const int o = blockIdx.x * 256 + threadIdx.x;
    const float* Bn = B + (size_t)n * RANK * O_DIM + o;
    unsigned short tmp[RANK];
#pragma unroll
    for (int r = 0; r < RANK; ++r)
        tmp[r] = f2bf(Bn[(size_t)r * O_DIM]);
    s16x8* dst = (s16x8*)(BTb + ((size_t)n * O_DIM + o) * RANK);
    dst[0] = *(const s16x8*)&tmp[0];
    dst[1] = *(const s16x8*)&tmp[8];
}

// ---------------- fused: per 16-token tile, MFMA shrink then MFMA expand ----------------
// Phase 1: wave w = K-quarter of [16tok x 4096] @ [4096 x 16r] -> vp[w] -> vsum (LDS).
// Phase 2: D[col][tok] = BT-tile(16 cols, K=32 zero-padded ranks) x V^T.
//   A-frag: lane m=col=mi, k=kg*8+j  -> BTb[o+mi][kg*8..+7] (16B, L2-hot; kg>=2 -> 0)
//   B-frag: lane n=tok=mi, k=kg*8+j  -> bf16(vsum[mi][kg*8..+7]) loop-invariant (kg>=2 -> 0)
//   D:      lane: tok=mi, outcols kg*4+q -> ONE contiguous f32x4 of result/out per lane.

__global__ __launch_bounds__(256, 4) void k_fused(
    const float* __restrict__ result, const float* __restrict__ x,
    const unsigned short* __restrict__ atb, const unsigned short* __restrict__ btb,
    const int* __restrict__ order, const int* __restrict__ counts,
    const int* __restrict__ offs, float* __restrict__ out) {

    // block -> (adapter n, tile)
    const int bid = blockIdx.x;
    int n = 0, tile = 0, found = 0, acc_t = 0;
#pragma unroll
    for (int i = 0; i < NA; ++i) {
        int tn = (counts[i] + 15) >> 4;
        if (!found && bid < acc_t + tn) { n = i; tile = bid - acc_t; found = 1; }
        acc_t += tn;
    }
    if (!found) return;
    const int cnt = counts[n];
    const int seg = offs[n];
    const int tbase = tile << 4;
    const int np = min(16, cnt - tbase);

    __shared__ float vp[4][16][16];
    __shared__ float vsum[16][16];
    __shared__ int toks[16];

    const int w = threadIdx.x >> 6, lane = threadIdx.x & 63;
    const int mi = lane & 15, kg = lane >> 4;

    if (threadIdx.x < 16)
        toks[threadIdx.x] = order[seg + min(tbase + (int)threadIdx.x, cnt - 1)];

    // ---- phase 1: shrink quarter kc = w ----
    {
        const int tokm = order[seg + min(tbase + mi, cnt - 1)];
        const float* xp = x + (size_t)tokm * H_DIM + w * 1024 + kg * 8;
        const unsigned short* bp0 = atb + ((size_t)n * RANK + mi) * H_DIM + w * 1024 + kg * 8;

        f32x4 acc = {0.f, 0.f, 0.f, 0.f};
#pragma unroll 8
        for (int ks = 0; ks < 32; ++ks) {
            f32x4 xlo = *(const f32x4*)(xp + ks * 32);
            f32x4 xhi = *(const f32x4*)(xp + ks * 32 + 4);
            bf16x8 bfrag = *(const bf16x8*)(bp0 + ks * 32);
            bf16x8 afrag;
            afrag[0] = (short)f2bf(xlo.x); afrag[1] = (short)f2bf(xlo.y);
            afrag[2] = (short)f2bf(xlo.z); afrag[3] = (short)f2bf(xlo.w);
            afrag[4] = (short)f2bf(xhi.x); afrag[5] = (short)f2bf(xhi.y);
            afrag[6] = (short)f2bf(xhi.z); afrag[7] = (short)f2bf(xhi.w);
            acc = __builtin_amdgcn_mfma_f32_16x16x32_bf16(afrag, bfrag, acc, 0, 0, 0);
        }
#pragma unroll
        for (int q = 0; q < 4; ++q)
            vp[w][kg * 4 + q][mi] = acc[q];
    }
    __syncthreads();
    {
        const int p = threadIdx.x >> 4, r = threadIdx.x & 15;
        vsum[p][r] = (vp[0][p][r] + vp[1][p][r]) + (vp[2][p][r] + vp[3][p][r]);
    }
    __syncthreads();

    // ---- phase 2: MFMA expand, wave w covers cols [w*1024, w*1024+1024) ----
    bf16x8 vf = {0, 0, 0, 0, 0, 0, 0, 0};
    if (kg < 2) {
        const float* vsrc = &vsum[mi][kg * 8];
#pragma unroll
        for (int j = 0; j < 8; ++j) vf[j] = (short)f2bf(vsrc[j]);
    }

    const unsigned short* BTn = btb + (size_t)n * O_DIM * RANK;
    const size_t rowoff = (size_t)toks[mi] * O_DIM + kg * 4;
    const bool live = (mi < np);
    const int oc0 = w * 1024;

#pragma unroll 4
    for (int oc = oc0; oc < oc0 + 1024; oc += 16) {
        bf16x8 af = {0, 0, 0, 0, 0, 0, 0, 0};
        if (kg < 2)
            af = *(const bf16x8*)(BTn + (size_t)(oc + mi) * RANK + kg * 8);
        f32x4 z = {0.f, 0.f, 0.f, 0.f};
        f32x4 d = __builtin_amdgcn_mfma_f32_16x16x32_bf16(af, vf, z, 0, 0, 0);
        const size_t off = rowoff + oc;
        f32x4 rv = __builtin_nontemporal_load((const f32x4*)(result + off));
        d += rv;
        if (live)
            __builtin_nontemporal_store(d, (f32x4*)(out + off));
    }
}

// ---------------- launch ----------------

extern "C" void kernel_launch(void* const* d_in, const int* in_sizes, int n_in,
                              void* d_out, int out_size, void* d_ws, size_t ws_size,
                              hipStream_t stream) {
    const float* result = (const float*)d_in[0];
    const float* x      = (const float*)d_in[1];
    const float* lora_a = (const float*)d_in[2];
    const float* lora_b = (const float*)d_in[3];
    const int*   aidx   = (const int*)d_in[4];
    float* out = (float*)d_out;

    int* order  = (int*)d_ws;
    int* counts = order + T_TOK;
    int* offs   = counts + NA;
    int* cursor = offs + NA;
    unsigned short* ATb = (unsigned short*)(cursor + NA);            // 1 MB
    unsigned short* BTb = ATb + (size_t)NA * RANK * H_DIM;           // 1 MB

    k_zero<<<dim3(1), dim3(64), 0, stream>>>(counts);
    k_hist<<<dim3(64), dim3(256), 0, stream>>>(aidx, counts);
    k_prefix<<<dim3(1), dim3(64), 0, stream>>>(counts, offs, cursor);
    k_scatter<<<dim3(64), dim3(256), 0, stream>>>(aidx, cursor, order);
    k_transpose<<<dim3(16, NA), dim3(256), 0, stream>>>(lora_a, ATb);
    k_transposeB<<<dim3(16, NA), dim3(256), 0, stream>>>(lora_b, BTb);
    k_fused<<<dim3(T_TOK / 16 + NA), dim3(256), 0, stream>>>(
        result, x, ATb, BTb, order, counts, offs, out);
}

// Round 10
// 236.212 us; speedup vs baseline: 1.6842x; 1.6842x over previous
//
#include <hip/hip_runtime.h>

#define T_TOK 16384
#define H_DIM 4096
#define O_DIM 4096
#define NA 8
#define RANK 16
#define NKC 8              // K-slices of 512 cols
#define NPE 32             // tokens per expand block

typedef float f32x4 __attribute__((ext_vector_type(4)));
typedef short bf16x8 __attribute__((ext_vector_type(8)));

struct ushort4s { unsigned short x, y, z, w; };

// f32 -> bf16 (RTNE)
static __device__ __forceinline__ unsigned short f2bf(float f) {
    unsigned int u = __float_as_uint(f);
    u = (u + 0x7fffu + ((u >> 16) & 1u)) >> 16;
    return (unsigned short)u;
}
static __device__ __forceinline__ float bf2f(unsigned short s) {
    return __uint_as_float(((unsigned int)s) << 16);
}

// ---------------- sort-by-adapter machinery ----------------

__global__ void k_zero(int* __restrict__ counts) {
    if (threadIdx.x < NA) counts[threadIdx.x] = 0;
}

__global__ void k_hist(const int* __restrict__ idx, int* __restrict__ counts) {
    __shared__ int h[NA];
    if (threadIdx.x < NA) h[threadIdx.x] = 0;
    __syncthreads();
    int t = blockIdx.x * blockDim.x + threadIdx.x;
    atomicAdd(&h[idx[t]], 1);
    __syncthreads();
    if (threadIdx.x < NA) atomicAdd(&counts[threadIdx.x], h[threadIdx.x]);
}

__global__ void k_prefix(const int* __restrict__ counts, int* __restrict__ offs,
                         int* __restrict__ cursor) {
    if (threadIdx.x == 0) {
        int run = 0;
        for (int n = 0; n < NA; n++) { offs[n] = run; cursor[n] = run; run += counts[n]; }
    }
}

__global__ void k_scatter(const int* __restrict__ idx, int* __restrict__ cursor,
                          int* __restrict__ order) {
    int t = blockIdx.x * blockDim.x + threadIdx.x;
    int a = idx[t];
    int lane = threadIdx.x & 63;
    for (int n = 0; n < NA; n++) {
        unsigned long long m = __ballot(a == n);
        if (m) {
            int leader = __ffsll((unsigned long long)m) - 1;
            int cnt = __popcll(m);
            int base = 0;
            if (lane == leader) base = atomicAdd(&cursor[n], cnt);
            base = __shfl(base, leader);
            if (a == n) {
                int rank = __popcll(m & ((1ull << lane) - 1ull));
                order[base + rank] = t;
            }
        }
    }
}

// ---------------- transpose A -> ATb[n][r][h] (bf16) ----------------

__global__ void k_transpose(const float* __restrict__ A, unsigned short* __restrict__ ATb) {
    const int n = blockIdx.y;
    const int h0 = blockIdx.x * 256;
    __shared__ float lds[256 * 17];
    const float4* src = (const float4*)(A + ((size_t)n * H_DIM + h0) * RANK);
#pragma unroll
    for (int k = 0; k < 4; ++k) {
        int f = k * 256 + threadIdx.x;
        float4 v = src[f];
        int row = (f * 4) >> 4, col = (f * 4) & 15;
        lds[row * 17 + col + 0] = v.x;
        lds[row * 17 + col + 1] = v.y;
        lds[row * 17 + col + 2] = v.z;
        lds[row * 17 + col + 3] = v.w;
    }
    __syncthreads();
    unsigned short* dst = ATb + (size_t)n * RANK * H_DIM;
#pragma unroll
    for (int r = 0; r < RANK; ++r)
        dst[(size_t)r * H_DIM + h0 + threadIdx.x] = f2bf(lds[threadIdx.x * 17 + r]);
}

// ---------------- shrink via MFMA: P[kc][t][r], kc = 512-col K-slice ----------------
// grid (32, NKC, 8), block 256 = 4 waves -> 2048 blocks = 8 waves/SIMD.
// Wave owns one 16-token tile (grid-stride). Dual acc chains (ks / ks+8) halve
// the serial MFMA depth. mfma_f32_16x16x32_bf16; A = x rows (f32->bf16 in reg),
// B = ATb rows (bf16, L2-hot).

__global__ __launch_bounds__(256, 4) void k_shrink_mfma(
    const float* __restrict__ x, const unsigned short* __restrict__ atb,
    const int* __restrict__ order, const int* __restrict__ counts,
    const int* __restrict__ offs, float* __restrict__ P) {
    const int n = blockIdx.z;
    const int cnt = counts[n];
    if (cnt == 0) return;
    const int seg = offs[n];
    const int w = threadIdx.x >> 6, lane = threadIdx.x & 63;
    const int kc = blockIdx.y;
    const int mi = lane & 15, kg = lane >> 4;
    const int tiles = (cnt + 15) >> 4;

    const unsigned short* bp0 = atb + ((size_t)n * RANK + mi) * H_DIM + kc * 512 + kg * 8;

    for (int tile = blockIdx.x * 4 + w; tile < tiles; tile += 128) {
        const int tbase = tile << 4;
        const int tok = order[seg + min(tbase + mi, cnt - 1)];
        const float* xp = x + (size_t)tok * H_DIM + kc * 512 + kg * 8;

        f32x4 acc0 = {0.f, 0.f, 0.f, 0.f};
        f32x4 acc1 = {0.f, 0.f, 0.f, 0.f};
#pragma unroll
        for (int ks = 0; ks < 8; ++ks) {
            {
                f32x4 xlo = *(const f32x4*)(xp + ks * 32);
                f32x4 xhi = *(const f32x4*)(xp + ks * 32 + 4);
                bf16x8 bfrag = *(const bf16x8*)(bp0 + ks * 32);
                bf16x8 afrag;
                afrag[0] = (short)f2bf(xlo.x); afrag[1] = (short)f2bf(xlo.y);
                afrag[2] = (short)f2bf(xlo.z); afrag[3] = (short)f2bf(xlo.w);
                afrag[4] = (short)f2bf(xhi.x); afrag[5] = (short)f2bf(xhi.y);
                afrag[6] = (short)f2bf(xhi.z); afrag[7] = (short)f2bf(xhi.w);
                acc0 = __builtin_amdgcn_mfma_f32_16x16x32_bf16(afrag, bfrag, acc0, 0, 0, 0);
            }
            {
                f32x4 xlo = *(const f32x4*)(xp + ks * 32 + 256);
                f32x4 xhi = *(const f32x4*)(xp + ks * 32 + 260);
                bf16x8 bfrag = *(const bf16x8*)(bp0 + ks * 32 + 256);
                bf16x8 afrag;
                afrag[0] = (short)f2bf(xlo.x); afrag[1] = (short)f2bf(xlo.y);
                afrag[2] = (short)f2bf(xlo.z); afrag[3] = (short)f2bf(xlo.w);
                afrag[4] = (short)f2bf(xhi.x); afrag[5] = (short)f2bf(xhi.y);
                afrag[6] = (short)f2bf(xhi.z); afrag[7] = (short)f2bf(xhi.w);
                acc1 = __builtin_amdgcn_mfma_f32_16x16x32_bf16(afrag, bfrag, acc1, 0, 0, 0);
            }
        }
        f32x4 acc = acc0 + acc1;
#pragma unroll
        for (int q = 0; q < 4; ++q) {
            int pr = tbase + kg * 4 + q;
            if (pr < cnt)
                P[((size_t)kc * T_TOK + seg + pr) * RANK + mi] = acc[q];
        }
    }
}

// ---------------- expand: out[t] = result[t] + (sum_kc P[kc][t]) @ B[n] ----------------
// grid (4, 512, 8), block 256. B col-quarter staged in LDS as bf16 (32 KB,
// conflict-free 8B-stride reads) -> no register-slice remat. 3-deep NT result
// prefetch; NT store.

__global__ __launch_bounds__(256, 2) void k_expand(
    const float* __restrict__ result, const float* __restrict__ lora_b,
    const float* __restrict__ P, const int* __restrict__ order,
    const int* __restrict__ counts, const int* __restrict__ offs,
    float* __restrict__ out) {
    const int n = blockIdx.z;
    const int cnt = counts[n];
    const int pbase = blockIdx.y * NPE;
    if (pbase >= cnt) return;
    const int seg = offs[n];
    const int oq = blockIdx.x * 1024;
    const int o0 = oq + (threadIdx.x << 2);

    __shared__ unsigned short blds[RANK][1024];   // 32 KB
    __shared__ float vlds[NPE * RANK];            // 2 KB
    __shared__ int olds[NPE];

    const int np = min(NPE, cnt - pbase);

    // stage B quarter (bf16): iteration k stages rank-row k, fully coalesced
    const float* Bn = lora_b + (size_t)n * RANK * O_DIM + oq;
#pragma unroll
    for (int r = 0; r < RANK; ++r) {
        f32x4 v = *(const f32x4*)(Bn + (size_t)r * O_DIM + (threadIdx.x << 2));
        ushort4s u;
        u.x = f2bf(v.x); u.y = f2bf(v.y); u.z = f2bf(v.z); u.w = f2bf(v.w);
        *(ushort4s*)&blds[r][threadIdx.x << 2] = u;
    }
    // stage V = sum of NKC partials
    if (threadIdx.x < np * 4) {
        const f32x4* Pb = (const f32x4*)P + (size_t)(seg + pbase) * 4 + threadIdx.x;
        f32x4 s = Pb[0];
#pragma unroll
        for (int c = 1; c < NKC; ++c) s += Pb[(size_t)c * T_TOK * 4];
        ((f32x4*)vlds)[threadIdx.x] = s;
    }
    if (threadIdx.x < np) olds[threadIdx.x] = order[seg + pbase + threadIdx.x];

    __syncthreads();

    size_t offA = (size_t)olds[0] * O_DIM + o0;
    f32x4 rA = __builtin_nontemporal_load((const f32x4*)(result + offA));
    size_t offB = offA, offC = offA;
    f32x4 rB = rA, rC = rA;
    if (np > 1) {
        offB = (size_t)olds[1] * O_DIM + o0;
        rB = __builtin_nontemporal_load((const f32x4*)(result + offB));
    }
    if (np > 2) {
        offC = (size_t)olds[2] * O_DIM + o0;
        rC = __builtin_nontemporal_load((const f32x4*)(result + offC));
    }

    for (int p = 0; p < np; ++p) {
        f32x4 rD = rC;
        size_t offD = 0;
        if (p + 3 < np) {
            offD = (size_t)olds[p + 3] * O_DIM + o0;
            rD = __builtin_nontemporal_load((const f32x4*)(result + offD));
        }
        float va[RANK];
#pragma unroll
        for (int u = 0; u < 4; ++u)
            *(f32x4*)&va[u * 4] = *(const f32x4*)&vlds[p * RANK + u * 4];
        f32x4 acc = rA;
#pragma unroll
        for (int r = 0; r < RANK; ++r) {
            ushort4s u = *(const ushort4s*)&blds[r][threadIdx.x << 2];
            acc.x = fmaf(va[r], bf2f(u.x), acc.x);
            acc.y = fmaf(va[r], bf2f(u.y), acc.y);
            acc.z = fmaf(va[r], bf2f(u.z), acc.z);
            acc.w = fmaf(va[r], bf2f(u.w), acc.w);
        }
        __builtin_nontemporal_store(acc, (f32x4*)(out + offA));
        rA = rB; offA = offB;
        rB = rC; offB = offC;
        rC = rD; offC = offD;
    }
}

// ---------------- launch ----------------

extern "C" void kernel_launch(void* const* d_in, const int* in_sizes, int n_in,
                              void* d_out, int out_size, void* d_ws, size_t ws_size,
                              hipStream_t stream) {
    const float* result = (const float*)d_in[0];
    const float* x      = (const float*)d_in[1];
    const float* lora_a = (const float*)d_in[2];
    const float* lora_b = (const float*)d_in[3];
    const int*   aidx   = (const int*)d_in[4];
    float* out = (float*)d_out;

    const size_t pbytes = (size_t)NKC * T_TOK * RANK * 4;        // 8 MB
    float* P    = (float*)d_ws;
    int* order  = (int*)((char*)d_ws + pbytes);
    int* counts = order + T_TOK;
    int* offs   = counts + NA;
    int* cursor = offs + NA;
    unsigned short* ATb = (unsigned short*)(cursor + NA);        // 1 MB

    k_zero<<<dim3(1), dim3(64), 0, stream>>>(counts);
    k_hist<<<dim3(64), dim3(256), 0, stream>>>(aidx, counts);
    k_prefix<<<dim3(1), dim3(64), 0, stream>>>(counts, offs, cursor);
    k_scatter<<<dim3(64), dim3(256), 0, stream>>>(aidx, cursor, order);
    k_transpose<<<dim3(16, NA), dim3(256), 0, stream>>>(lora_a, ATb);
    k_shrink_mfma<<<dim3(32, NKC, NA), dim3(256), 0, stream>>>(x, ATb, order, counts, offs, P);
    k_expand<<<dim3(4, 512, NA), dim3(256), 0, stream>>>(result, lora_b, P, order, counts, offs, out);
}

// Round 11
// 216.076 us; speedup vs baseline: 1.8412x; 1.0932x over previous
//
#include <hip/hip_runtime.h>

#define T_TOK 16384
#define H_DIM 4096
#define O_DIM 4096
#define NA 8
#define RANK 16
#define CHUNK 256            // f32 cols staged per chunk
#define LROW 260             // padded LDS row stride (260%32=4 -> 2-way banks, free)
#define NCH (H_DIM / CHUNK)  // 16 chunks
#define NPE 32               // tokens per expand block

typedef float f32x4 __attribute__((ext_vector_type(4)));
typedef short bf16x8 __attribute__((ext_vector_type(8)));

struct ushort4s { unsigned short x, y, z, w; };

// f32 -> bf16 (RTNE)
static __device__ __forceinline__ unsigned short f2bf(float f) {
    unsigned int u = __float_as_uint(f);
    u = (u + 0x7fffu + ((u >> 16) & 1u)) >> 16;
    return (unsigned short)u;
}
static __device__ __forceinline__ float bf2f(unsigned short s) {
    return __uint_as_float(((unsigned int)s) << 16);
}

// async global->LDS, 16B per lane, dest = wave-uniform base + lane*16
#define GL2LDS(gsrc, ldst)                                                   \
    __builtin_amdgcn_global_load_lds(                                        \
        (const __attribute__((address_space(1))) unsigned int*)(gsrc),       \
        (__attribute__((address_space(3))) unsigned int*)(ldst), 16, 0, 0)

// ---------------- sort-by-adapter machinery ----------------

__global__ void k_zero(int* __restrict__ counts) {
    if (threadIdx.x < NA) counts[threadIdx.x] = 0;
}

__global__ void k_hist(const int* __restrict__ idx, int* __restrict__ counts) {
    __shared__ int h[NA];
    if (threadIdx.x < NA) h[threadIdx.x] = 0;
    __syncthreads();
    int t = blockIdx.x * blockDim.x + threadIdx.x;
    atomicAdd(&h[idx[t]], 1);
    __syncthreads();
    if (threadIdx.x < NA) atomicAdd(&counts[threadIdx.x], h[threadIdx.x]);
}

__global__ void k_prefix(const int* __restrict__ counts, int* __restrict__ offs,
                         int* __restrict__ cursor) {
    if (threadIdx.x == 0) {
        int run = 0;
        for (int n = 0; n < NA; n++) { offs[n] = run; cursor[n] = run; run += counts[n]; }
    }
}

__global__ void k_scatter(const int* __restrict__ idx, int* __restrict__ cursor,
                          int* __restrict__ order) {
    int t = blockIdx.x * blockDim.x + threadIdx.x;
    int a = idx[t];
    int lane = threadIdx.x & 63;
    for (int n = 0; n < NA; n++) {
        unsigned long long m = __ballot(a == n);
        if (m) {
            int leader = __ffsll((unsigned long long)m) - 1;
            int cnt = __popcll(m);
            int base = 0;
            if (lane == leader) base = atomicAdd(&cursor[n], cnt);
            base = __shfl(base, leader);
            if (a == n) {
                int rank = __popcll(m & ((1ull << lane) - 1ull));
                order[base + rank] = t;
            }
        }
    }
}

// ---------------- transpose A -> ATb[n][r][h] (bf16) ----------------

__global__ void k_transpose(const float* __restrict__ A, unsigned short* __restrict__ ATb) {
    const int n = blockIdx.y;
    const int h0 = blockIdx.x * 256;
    __shared__ float lds[256 * 17];
    const float4* src = (const float4*)(A + ((size_t)n * H_DIM + h0) * RANK);
#pragma unroll
    for (int k = 0; k < 4; ++k) {
        int f = k * 256 + threadIdx.x;
        float4 v = src[f];
        int row = (f * 4) >> 4, col = (f * 4) & 15;
        lds[row * 17 + col + 0] = v.x;
        lds[row * 17 + col + 1] = v.y;
        lds[row * 17 + col + 2] = v.z;
        lds[row * 17 + col + 3] = v.w;
    }
    __syncthreads();
    unsigned short* dst = ATb + (size_t)n * RANK * H_DIM;
#pragma unroll
    for (int r = 0; r < RANK; ++r)
        dst[(size_t)r * H_DIM + h0 + threadIdx.x] = f2bf(lds[threadIdx.x * 17 + r]);
}

// ---------------- shrink: async-staged MFMA tile, writes V[T][16] ----------------
// Block = 4 waves = one 16-token tile. K-chunks of 256 f32 double-buffered in LDS
// via global_load_lds (16KB in flight per block, no VGPR cost). Wave w computes
// K-subrange w*64..w*64+63 of each chunk (2 MFMAs); 4 partials LDS-reduced at end.

__global__ __launch_bounds__(256, 4) void k_shrink(
    const float* __restrict__ x, const unsigned short* __restrict__ atb,
    const int* __restrict__ order, const int* __restrict__ counts,
    const int* __restrict__ offs, float* __restrict__ V) {

    // block -> (adapter n, tile)
    const int bid = blockIdx.x;
    int n = 0, tile = 0, found = 0, acc_t = 0;
#pragma unroll
    for (int i = 0; i < NA; ++i) {
        int tn = (counts[i] + 15) >> 4;
        if (!found && bid < acc_t + tn) { n = i; tile = bid - acc_t; found = 1; }
        acc_t += tn;
    }
    if (!found) return;
    const int cnt = counts[n];
    const int seg = offs[n];
    const int tbase = tile << 4;
    const int np = min(16, cnt - tbase);

    __shared__ float xs[2][16][LROW];    // 33.2 KB
    __shared__ float vp[4][16][16];      // 4 KB

    const int w = threadIdx.x >> 6, lane = threadIdx.x & 63;
    const int mi = lane & 15, kg = lane >> 4;

    // tokens for this wave's 4 staged rows (uniform per wave)
    int tok_i[4];
#pragma unroll
    for (int i = 0; i < 4; ++i)
        tok_i[i] = order[seg + min(tbase + w * 4 + i, cnt - 1)];

    const unsigned short* bp0 = atb + ((size_t)n * RANK + mi) * H_DIM + kg * 8;

#define STAGE(c_, b_)                                                         \
    {                                                                         \
        _Pragma("unroll") for (int i_ = 0; i_ < 4; ++i_) {                    \
            const int rr_ = w * 4 + i_;                                       \
            const float* src_ =                                               \
                x + (size_t)tok_i[i_] * H_DIM + (c_) * CHUNK + (lane << 2);   \
            GL2LDS(src_, &xs[b_][rr_][0]);                                    \
        }                                                                     \
    }

    f32x4 acc = {0.f, 0.f, 0.f, 0.f};

    STAGE(0, 0);
    __syncthreads();
    for (int c = 0; c < NCH; ++c) {
        if (c + 1 < NCH) STAGE(c + 1, (c + 1) & 1);
        const int b = c & 1;
        const int cb = w * 64;
#pragma unroll
        for (int ks = 0; ks < 2; ++ks) {
            const float* lsrc = &xs[b][mi][cb + ks * 32 + kg * 8];
            f32x4 xlo = *(const f32x4*)lsrc;
            f32x4 xhi = *(const f32x4*)(lsrc + 4);
            bf16x8 bfrag = *(const bf16x8*)(bp0 + (size_t)c * CHUNK + cb + ks * 32);
            bf16x8 afrag;
            afrag[0] = (short)f2bf(xlo.x); afrag[1] = (short)f2bf(xlo.y);
            afrag[2] = (short)f2bf(xlo.z); afrag[3] = (short)f2bf(xlo.w);
            afrag[4] = (short)f2bf(xhi.x); afrag[5] = (short)f2bf(xhi.y);
            afrag[6] = (short)f2bf(xhi.z); afrag[7] = (short)f2bf(xhi.w);
            acc = __builtin_amdgcn_mfma_f32_16x16x32_bf16(afrag, bfrag, acc, 0, 0, 0);
        }
        __syncthreads();   // drains stage(c+1) (vmcnt 0) + buffer-reuse sync
    }
#undef STAGE

#pragma unroll
    for (int q = 0; q < 4; ++q)
        vp[w][kg * 4 + q][mi] = acc[q];
    __syncthreads();
    {
        const int p = threadIdx.x >> 4, r = threadIdx.x & 15;
        if (p < np) {
            float s = (vp[0][p][r] + vp[1][p][r]) + (vp[2][p][r] + vp[3][p][r]);
            V[(size_t)(seg + tbase + p) * RANK + r] = s;
        }
    }
}

// ---------------- expand: out[t] = result[t] + V[t] @ B[n] ----------------
// grid (4, 512, 8), block 256. B col-quarter in LDS as bf16 (32 KB); 3-deep NT
// result prefetch; NT store.

__global__ __launch_bounds__(256, 3) void k_expand(
    const float* __restrict__ result, const float* __restrict__ lora_b,
    const float* __restrict__ V, const int* __restrict__ order,
    const int* __restrict__ counts, const int* __restrict__ offs,
    float* __restrict__ out) {
    const int n = blockIdx.z;
    const int cnt = counts[n];
    const int pbase = blockIdx.y * NPE;
    if (pbase >= cnt) return;
    const int seg = offs[n];
    const int oq = blockIdx.x * 1024;
    const int o0 = oq + (threadIdx.x << 2);

    __shared__ unsigned short blds[RANK][1024];   // 32 KB
    __shared__ float vlds[NPE * RANK];            // 2 KB
    __shared__ int olds[NPE];

    const int np = min(NPE, cnt - pbase);

    const float* Bn = lora_b + (size_t)n * RANK * O_DIM + oq;
#pragma unroll
    for (int r = 0; r < RANK; ++r) {
        f32x4 v = *(const f32x4*)(Bn + (size_t)r * O_DIM + (threadIdx.x << 2));
        ushort4s u;
        u.x = f2bf(v.x); u.y = f2bf(v.y); u.z = f2bf(v.z); u.w = f2bf(v.w);
        *(ushort4s*)&blds[r][threadIdx.x << 2] = u;
    }
    if (threadIdx.x < np * 4)
        ((f32x4*)vlds)[threadIdx.x] =
            ((const f32x4*)V)[(size_t)(seg + pbase) * 4 + threadIdx.x];
    if (threadIdx.x < np) olds[threadIdx.x] = order[seg + pbase + threadIdx.x];

    __syncthreads();

    size_t offA = (size_t)olds[0] * O_DIM + o0;
    f32x4 rA = __builtin_nontemporal_load((const f32x4*)(result + offA));
    size_t offB = offA, offC = offA;
    f32x4 rB = rA, rC = rA;
    if (np > 1) {
        offB = (size_t)olds[1] * O_DIM + o0;
        rB = __builtin_nontemporal_load((const f32x4*)(result + offB));
    }
    if (np > 2) {
        offC = (size_t)olds[2] * O_DIM + o0;
        rC = __builtin_nontemporal_load((const f32x4*)(result + offC));
    }

    for (int p = 0; p < np; ++p) {
        f32x4 rD = rC;
        size_t offD = 0;
        if (p + 3 < np) {
            offD = (size_t)olds[p + 3] * O_DIM + o0;
            rD = __builtin_nontemporal_load((const f32x4*)(result + offD));
        }
        float va[RANK];
#pragma unroll
        for (int u = 0; u < 4; ++u)
            *(f32x4*)&va[u * 4] = *(const f32x4*)&vlds[p * RANK + u * 4];
        f32x4 acc = rA;
#pragma unroll
        for (int r = 0; r < RANK; ++r) {
            ushort4s u = *(const ushort4s*)&blds[r][threadIdx.x << 2];
            acc.x = fmaf(va[r], bf2f(u.x), acc.x);
            acc.y = fmaf(va[r], bf2f(u.y), acc.y);
            acc.z = fmaf(va[r], bf2f(u.z), acc.z);
            acc.w = fmaf(va[r], bf2f(u.w), acc.w);
        }
        __builtin_nontemporal_store(acc, (f32x4*)(out + offA));
        rA = rB; offA = offB;
        rB = rC; offB = offC;
        rC = rD; offC = offD;
    }
}

// ---------------- launch ----------------

extern "C" void kernel_launch(void* const* d_in, const int* in_sizes, int n_in,
                              void* d_out, int out_size, void* d_ws, size_t ws_size,
                              hipStream_t stream) {
    const float* result = (const float*)d_in[0];
    const float* x      = (const float*)d_in[1];
    const float* lora_a = (const float*)d_in[2];
    const float* lora_b = (const float*)d_in[3];
    const int*   aidx   = (const int*)d_in[4];
    float* out = (float*)d_out;

    float* V    = (float*)d_ws;                                  // 1 MB
    int* order  = (int*)((char*)d_ws + (size_t)T_TOK * RANK * 4);
    int* counts = order + T_TOK;
    int* offs   = counts + NA;
    int* cursor = offs + NA;
    unsigned short* ATb = (unsigned short*)(cursor + NA);        // 1 MB

    k_zero<<<dim3(1), dim3(64), 0, stream>>>(counts);
    k_hist<<<dim3(64), dim3(256), 0, stream>>>(aidx, counts);
    k_prefix<<<dim3(1), dim3(64), 0, stream>>>(counts, offs, cursor);
    k_scatter<<<dim3(64), dim3(256), 0, stream>>>(aidx, cursor, order);
    k_transpose<<<dim3(16, NA), dim3(256), 0, stream>>>(lora_a, ATb);
    k_shrink<<<dim3(T_TOK / 16 + NA), dim3(256), 0, stream>>>(
        x, ATb, order, counts, offs, V);
    k_expand<<<dim3(4, 512, NA), dim3(256), 0, stream>>>(
        result, lora_b, V, order, counts, offs, out);
}